// Round 2
// baseline (198.524 us; speedup 1.0000x reference)
//
#include <hip/hip_runtime.h>

// QNN closed form: q_b = prod_{i<8} cos(pi/2 + 2*x_bi) = prod_{i<8} sin(2*x_bi)
// (8 negative signs cancel). out[b,0] = s*q, out[b,1] = -s*q.
//
// Coalescing scheme: thread t handles float4 chunks t and t+half (half =
// B*2/2). Two threads per row: lane pair (2k, 2k+1) holds the two halves of
// row k; __shfl_xor(…,1) combines the 4-factor partial products. Loads are
// 16B/lane unit-stride per instruction, stores 4B/lane unit-stride — both
// perfectly coalesced. Two independent chunks per thread = 2 loads in flight
// before any dependent op (ILP/MLP), half the wave count of the 1-chunk
// version.

__global__ __launch_bounds__(256) void qnn_kernel(const float4* __restrict__ x4,
                                                  const float* __restrict__ scale_p,
                                                  float* __restrict__ out,
                                                  int half) {
    int t = blockIdx.x * blockDim.x + threadIdx.x;
    if (t >= half) return;

    // Issue both loads before any dependent compute.
    float4 a = x4[t];
    float4 b = x4[t + half];
    float s = scale_p[0];

    // __sinf: v_mul(1/2pi) + v_sin_f32; |2x| <~ 12 rad for N(0,1) -> accurate.
    float pa = __sinf(2.0f * a.x) * __sinf(2.0f * a.y) *
               __sinf(2.0f * a.z) * __sinf(2.0f * a.w);
    float pb = __sinf(2.0f * b.x) * __sinf(2.0f * b.y) *
               __sinf(2.0f * b.z) * __sinf(2.0f * b.w);

    float qa = pa * __shfl_xor(pa, 1, 64);   // full 8-factor row product
    float qb = pb * __shfl_xor(pb, 1, 64);

    float sg = (t & 1) ? -s : s;             // col 0 -> +s, col 1 -> -s
    out[t]        = sg * qa;
    out[t + half] = sg * qb;
}

extern "C" void kernel_launch(void* const* d_in, const int* in_sizes, int n_in,
                              void* d_out, int out_size, void* d_ws, size_t ws_size,
                              hipStream_t stream) {
    const float4* x4    = (const float4*)d_in[0];   // [B,8] fp32 = [B*2] float4
    const float*  scale = (const float*)d_in[2];    // scalar (d_in[1] = weights, unused)
    float*        out   = (float*)d_out;            // [B,2] fp32 flat = B*2 floats

    int n4   = in_sizes[0] / 4;                     // B*2 chunks == out elements
    int half = n4 / 2;                              // 2 chunks per thread
    int block = 256;
    int grid = (half + block - 1) / block;
    qnn_kernel<<<grid, block, 0, stream>>>(x4, scale, out, half);
}